// Round 1
// baseline (265.914 us; speedup 1.0000x reference)
//
#include <hip/hip_runtime.h>

#define B_TOTAL 131072
#define N 19
#define BB 13                 // batches per block-iteration (13*19=247 <= 256 threads)
#define ROWS (BB * N)         // 247 active row-threads
#define NPAD 20               // padded row length: 80B, 16B-aligned rows for float4 LDS reads
#define OUT_PER_G (BB * N * N) // 4693 floats staged per block-iteration

// ---------------------------------------------------------------------------
// Prep: c[j] = mean_i corr[i][j]  (folds the .mean(axis=-1) of K @ corr.T)
// ---------------------------------------------------------------------------
__global__ void cga_prep(const float* __restrict__ corr, float* __restrict__ c) {
    int t = threadIdx.x;
    if (t < N) {
        float s = 0.f;
#pragma unroll
        for (int i = 0; i < N; ++i) s += corr[i * N + t];
        c[t] = s * (1.0f / N);
    }
}

// ---------------------------------------------------------------------------
// Main kernel: one thread per (batch, query-row i).
//   out[b,i,k] = feat[b,k] + bo[k] + invZ_i * sum_j exp(a_i*K_j - m_i)*V_j*Wo[k,j]
//   a_i = Q_i * (K . c) / T
// Wo/bo/c accessed with wave-uniform indices -> scalar (SMEM) loads, SGPR FMA
// operands. Output staged in LDS, stored flat & coalesced.
// ---------------------------------------------------------------------------
__global__ void __launch_bounds__(256) cga_kernel(
    const float* __restrict__ feats,
    const float* __restrict__ Wq, const float* __restrict__ bq,
    const float* __restrict__ Wk, const float* __restrict__ bk,
    const float* __restrict__ Wv, const float* __restrict__ bv,
    const float* __restrict__ Wo, const float* __restrict__ bo,
    const float* __restrict__ temp,
    const float* __restrict__ c,
    float* __restrict__ out)
{
    __shared__ __align__(16) float feat_s[BB * NPAD];
    __shared__ __align__(16) float k_s[BB * NPAD];
    __shared__ __align__(16) float v_s[BB * NPAD];
    __shared__ __align__(16) float out_s[OUT_PER_G];

    const int t = threadIdx.x;
    const int bl = t / N;          // local batch 0..12 (for t < 247)
    const int i  = t - bl * N;     // query row 0..18
    const bool active = (t < ROWS);

    // Per-thread weight rows: depend only on i -> load once, reuse for all
    // grid-stride iterations (stays in VGPRs).
    float wq[N], wk[N], wv[N];
    float bqv = 0.f, bkv = 0.f, bvv = 0.f;
    if (active) {
#pragma unroll
        for (int j = 0; j < N; ++j) {
            wq[j] = Wq[i * N + j];
            wk[j] = Wk[i * N + j];
            wv[j] = Wv[i * N + j];
        }
        bqv = bq[i]; bkv = bk[i]; bvv = bv[i];
    }
    const float invT = 1.0f / temp[0];

    const int G = (B_TOTAL + BB - 1) / BB;   // 10083 batch-groups
    for (int g = blockIdx.x; g < G; g += gridDim.x) {
        const int b0 = g * BB;

        // ---- stage features for 13 batches (one coalesced load) ----
        if (t < ROWS) {
            int gidx = b0 * N + t;
            float v = (gidx < B_TOTAL * N) ? feats[gidx] : 0.f;
            feat_s[(t / N) * NPAD + (t % N)] = v;
        }
        __syncthreads();

        float f[NPAD];
        float q_i = 0.f, k_i = 0.f, v_i = 0.f;
        if (active) {
            const float4* fp = (const float4*)(&feat_s[bl * NPAD]);
#pragma unroll
            for (int c4 = 0; c4 < 5; ++c4) {
                float4 x = fp[c4];
                f[c4*4+0] = x.x; f[c4*4+1] = x.y; f[c4*4+2] = x.z; f[c4*4+3] = x.w;
            }
            q_i = bqv; k_i = bkv; v_i = bvv;
#pragma unroll
            for (int j = 0; j < N; ++j) {
                q_i = fmaf(f[j], wq[j], q_i);
                k_i = fmaf(f[j], wk[j], k_i);
                v_i = fmaf(f[j], wv[j], v_i);
            }
            k_s[bl * NPAD + i] = k_i;
            v_s[bl * NPAD + i] = v_i;
        }
        __syncthreads();

        if (active) {
            float K[NPAD], V[NPAD];
            const float4* kp = (const float4*)(&k_s[bl * NPAD]);
            const float4* vp = (const float4*)(&v_s[bl * NPAD]);
#pragma unroll
            for (int c4 = 0; c4 < 5; ++c4) {
                float4 x = kp[c4];
                K[c4*4+0] = x.x; K[c4*4+1] = x.y; K[c4*4+2] = x.z; K[c4*4+3] = x.w;
                float4 y = vp[c4];
                V[c4*4+0] = y.x; V[c4*4+1] = y.y; V[c4*4+2] = y.z; V[c4*4+3] = y.w;
            }
            // correlation weight (c[] is wave-uniform -> SGPR operand)
            float cw = 0.f;
#pragma unroll
            for (int j = 0; j < N; ++j) cw = fmaf(c[j], K[j], cw);
            const float a = q_i * cw * invT;

            // softmax row i over j, fused with V
            float s[N];
            float m = -1e30f;
#pragma unroll
            for (int j = 0; j < N; ++j) { s[j] = a * K[j]; m = fmaxf(m, s[j]); }
            float z = 0.f;
            float qv[N];
#pragma unroll
            for (int j = 0; j < N; ++j) {
                float e = __expf(s[j] - m);
                qv[j] = e * V[j];
                z += e;
            }
            const float invZ = 1.0f / z;

            // contraction with Wo (wave-uniform literal indices -> s_load +
            // v_fmac with SGPR source; keeps LDS pipe free)
            const int obase = t * N;   // == bl*361 + i*19
#pragma unroll
            for (int k = 0; k < N; ++k) {
                float acc = 0.f;
#pragma unroll
                for (int j = 0; j < N; ++j) acc = fmaf(qv[j], Wo[k * N + j], acc);
                out_s[obase + k] = f[k] + bo[k] + acc * invZ;
            }
        }
        __syncthreads();

        // ---- flat, fully-coalesced store of the 13*361 staged outputs ----
        const int outbase = b0 * (N * N);
#pragma unroll
        for (int r = 0; r < (OUT_PER_G + 255) / 256; ++r) {
            int idx = r * 256 + t;
            int go = outbase + idx;
            if (idx < OUT_PER_G && go < B_TOTAL * N * N)
                out[go] = out_s[idx];
        }
        __syncthreads();  // protect feat_s/out_s before next iteration
    }
}

extern "C" void kernel_launch(void* const* d_in, const int* in_sizes, int n_in,
                              void* d_out, int out_size, void* d_ws, size_t ws_size,
                              hipStream_t stream) {
    const float* feats = (const float*)d_in[0];
    const float* Wq    = (const float*)d_in[1];
    const float* bq    = (const float*)d_in[2];
    const float* Wk    = (const float*)d_in[3];
    const float* bk    = (const float*)d_in[4];
    const float* Wv    = (const float*)d_in[5];
    const float* bv    = (const float*)d_in[6];
    const float* Wo    = (const float*)d_in[7];
    const float* bo    = (const float*)d_in[8];
    const float* corr  = (const float*)d_in[9];
    const float* temp  = (const float*)d_in[10];
    float* out = (float*)d_out;
    float* c   = (float*)d_ws;   // 19 floats of scratch; recomputed every call

    cga_prep<<<1, 64, 0, stream>>>(corr, c);
    cga_kernel<<<1024, 256, 0, stream>>>(feats, Wq, bq, Wk, bk, Wv, bv, Wo, bo,
                                         temp, c, out);
}

// Round 2
// 244.263 us; speedup vs baseline: 1.0886x; 1.0886x over previous
//
#include <hip/hip_runtime.h>

#define B_TOTAL 131072
#define N 19
#define BB 13                  // batches per block (13*19 = 247 active threads of 256)
#define ROWS (BB * N)          // 247
#define NPAD 20                // padded row: 80 B, 16B-aligned rows for float4 LDS reads
#define OUT_PER_G (BB * N * N) // 4693 floats staged per block
#define NBLOCKS ((B_TOTAL + BB - 1) / BB)  // 10083 (last block: 6 valid batches)

// One block = 13 batches. One thread = one (batch, query-row i).
//   out[b,i,k] = feat[b,k] + bo[k] + invZ_i * sum_j exp(a_i*K_j - m_i)*V_j*Wo[k,j]
//   a_i = Q_i * (K . c) / T,  c[j] = mean_i corr[i,j]  (computed in-kernel)
// Phases: stage feats + c -> barrier -> QKV -> barrier -> softmax+contraction
// into LDS -> barrier -> flat coalesced store. No grid-stride loop: weight
// registers are phase-local, VGPR peak ~100 -> 4+ waves/SIMD.
__global__ void __launch_bounds__(256, 4) cga_kernel(
    const float* __restrict__ feats,
    const float* __restrict__ Wq, const float* __restrict__ bq,
    const float* __restrict__ Wk, const float* __restrict__ bk,
    const float* __restrict__ Wv, const float* __restrict__ bv,
    const float* __restrict__ Wo, const float* __restrict__ bo,
    const float* __restrict__ corr,
    const float* __restrict__ temp,
    float* __restrict__ out)
{
    __shared__ __align__(16) float feat_s[BB * NPAD];
    __shared__ __align__(16) float k_s[BB * NPAD];
    __shared__ __align__(16) float v_s[BB * NPAD];
    __shared__ __align__(16) float c_s[NPAD];
    __shared__ __align__(16) float out_s[OUT_PER_G];

    const int t  = threadIdx.x;
    const int b0 = blockIdx.x * BB;
    const int bl = t / N;          // local batch 0..12 (t < 247)
    const int i  = t - bl * N;     // query row 0..18
    const bool active = (t < ROWS);

    // ---- phase 1: stage features (coalesced) + correlation column means ----
    if (active) {
        int gidx = b0 * N + t;
        // tail block: out-of-range batches read as 0 -> finite garbage rows
        // in out_s that the store phase never writes back.
        feat_s[bl * NPAD + i] = (gidx < B_TOTAL * N) ? feats[gidx] : 0.f;
    }
    if (t < N) {
        float s = 0.f;
#pragma unroll
        for (int r = 0; r < N; ++r) s += corr[r * N + t];
        c_s[t] = s * (1.0f / N);
    }
    const float invT = 1.0f / temp[0];
    __syncthreads();

    // ---- phase 2: Q/K/V projections (weight rows L1-hot, phase-local) ----
    float f[NPAD];
    float q_i = 0.f, k_i = 0.f, v_i = 0.f;
    if (active) {
        const float4* fp = (const float4*)(&feat_s[bl * NPAD]);
#pragma unroll
        for (int c4 = 0; c4 < 5; ++c4) {
            float4 x = fp[c4];
            f[c4*4+0] = x.x; f[c4*4+1] = x.y; f[c4*4+2] = x.z; f[c4*4+3] = x.w;
        }
        q_i = bq[i]; k_i = bk[i]; v_i = bv[i];
#pragma unroll
        for (int j = 0; j < N; ++j) {
            q_i = fmaf(f[j], Wq[i * N + j], q_i);
            k_i = fmaf(f[j], Wk[i * N + j], k_i);
            v_i = fmaf(f[j], Wv[i * N + j], v_i);
        }
        k_s[bl * NPAD + i] = k_i;
        v_s[bl * NPAD + i] = v_i;
    }
    __syncthreads();

    // ---- phase 3: cw, softmax (fused with V), Wo contraction ----
    if (active) {
        float K[NPAD], V[NPAD];
        const float4* kp = (const float4*)(&k_s[bl * NPAD]);
        const float4* vp = (const float4*)(&v_s[bl * NPAD]);
#pragma unroll
        for (int c4 = 0; c4 < 5; ++c4) {
            float4 x = kp[c4];
            K[c4*4+0] = x.x; K[c4*4+1] = x.y; K[c4*4+2] = x.z; K[c4*4+3] = x.w;
            float4 y = vp[c4];
            V[c4*4+0] = y.x; V[c4*4+1] = y.y; V[c4*4+2] = y.z; V[c4*4+3] = y.w;
        }
        float cw = 0.f;
#pragma unroll
        for (int j = 0; j < N; ++j) cw = fmaf(c_s[j], K[j], cw);
        const float a = q_i * cw * invT;

        // row max without storing scores (saves 19 regs at the peak)
        float m = -1e30f;
#pragma unroll
        for (int j = 0; j < N; ++j) m = fmaxf(m, a * K[j]);
        float z = 0.f;
        float p[N];
#pragma unroll
        for (int j = 0; j < N; ++j) {
            float e = __expf(fmaf(a, K[j], -m));
            p[j] = e * V[j];
            z += e;
        }
        const float invZ = 1.0f / z;

        // contraction with Wo: wave-uniform addresses -> scalar/broadcast,
        // L1-resident (1.4 KB)
        const int obase = t * N;
#pragma unroll
        for (int k = 0; k < N; ++k) {
            float acc = 0.f;
#pragma unroll
            for (int j = 0; j < N; ++j) acc = fmaf(p[j], Wo[k * N + j], acc);
            out_s[obase + k] = f[k] + bo[k] + acc * invZ;
        }
    }
    __syncthreads();

    // ---- phase 4: flat, fully-coalesced store of 13*361 staged floats ----
    const int outbase = b0 * (N * N);
#pragma unroll
    for (int r = 0; r < (OUT_PER_G + 255) / 256; ++r) {
        int idx = r * 256 + t;
        int go  = outbase + idx;
        if (idx < OUT_PER_G && go < B_TOTAL * N * N)
            out[go] = out_s[idx];
    }
}

extern "C" void kernel_launch(void* const* d_in, const int* in_sizes, int n_in,
                              void* d_out, int out_size, void* d_ws, size_t ws_size,
                              hipStream_t stream) {
    const float* feats = (const float*)d_in[0];
    const float* Wq    = (const float*)d_in[1];
    const float* bq    = (const float*)d_in[2];
    const float* Wk    = (const float*)d_in[3];
    const float* bk    = (const float*)d_in[4];
    const float* Wv    = (const float*)d_in[5];
    const float* bv    = (const float*)d_in[6];
    const float* Wo    = (const float*)d_in[7];
    const float* bo    = (const float*)d_in[8];
    const float* corr  = (const float*)d_in[9];
    const float* temp  = (const float*)d_in[10];
    float* out = (float*)d_out;

    cga_kernel<<<NBLOCKS, 256, 0, stream>>>(feats, Wq, bq, Wk, bk, Wv, bv,
                                            Wo, bo, corr, temp, out);
}